// Round 1
// baseline (2258.420 us; speedup 1.0000x reference)
//
#include <hip/hip_runtime.h>
#include <hip/hip_bf16.h>
#include <cstdint>

// Neural ODE: 10 Heun steps of f(y) = tanh(y@W1 + b1)@W2 + b2
// BATCH=8192, D=512, H=2048, dt=0.1
// R7: register-resident A. 256 blocks x 512 threads (8 waves, 2/SIMD,
// <=256 VGPR). Each wave holds its 32 y A-frags (128 VGPRs) for the whole
// eval -> GEMM1 reads ZERO bytes from LDS (was 4 MB/block/eval of yA
// re-reads, ~46% of the LDS pipe). Wider per-wave n-tiles (2 nb GEMM1,
// 4 nb2 GEMM2) keep weight L2 traffic at the blocking minimum (each B-frag
// read once per block). New floor: 4 MB/CU/eval weight stream from L2
// (~30 us/eval).

#define BATCHN 8192
#define DDIM 512
#define HDIM 2048
#define CW 256          // chunk width over H
#define NCH (HDIM / CW) // 8

typedef short short8 __attribute__((ext_vector_type(8)));
typedef float floatx4 __attribute__((ext_vector_type(4)));

__device__ __forceinline__ unsigned short f2bf(float f) {
  union { __hip_bfloat16 h; unsigned short u; } cv;
  cv.h = __float2bfloat16(f);
  return cv.u;
}

__device__ __forceinline__ float fast_tanh(float x) {
  float e = __expf(2.0f * x);
  return 1.0f - 2.0f / (e + 1.0f);
}

// Fragment conventions (verified by R1-R6 passing kernels):
//  A-frag (16x16x32): lane holds A[m = l15][k = quad*8 + j], j=0..7 (16B)
//  B-frag:            lane holds B[n = l15][k = quad*8 + j]  (BT row-major)
//  C/D:               row = quad*4 + r, col = l15
// Packed buffers: frag f stored at [(f*64 + lane)*8] halves.
//  yPack: f = rb*16 + ks   (rb = batch-row/16: 0..511, ks = D k-step: 0..15)
//  w1p:   f = nb*16 + kb   (nb = H col-tile: 0..127,   kb = D k-step: 0..15)
//  w2p:   f = nb*64 + kb   (nb = D col-tile: 0..31,    kb = H k-step: 0..63)

__global__ __launch_bounds__(512, 2) void fused_feval(
    const unsigned short* __restrict__ yPack,   // packed bf16 eval input
    const unsigned short* __restrict__ w1p,
    const unsigned short* __restrict__ w2p,
    const float* __restrict__ b1,
    const float* __restrict__ b2,
    const float* __restrict__ stateIn,   // EPI1: y fp32 ; EPI2: p fp32
    float* __restrict__ stateOut,        // EPI1: p      ; EPI2: ynew
    unsigned short* __restrict__ outPack,// packed bf16 next-eval input
    int epi) {                           // 1 or 2
  __shared__ unsigned short hA[2][32 * CW];     // 2 x 16 KB, frag (mt*8+ks)

  const int tid  = threadIdx.x;
  const int lane = tid & 63;
  const int w    = tid >> 6;    // wave 0..7
  const int quad = lane >> 4;
  const int l15  = lane & 15;
  const int blk  = blockIdx.x;  // 0..255
  const int B0   = blk * 32;    // slab base row

  // phase0: load this wave's 32 A-frags (the whole 32x512 slab) into regs.
  // 32 x global_load_dwordx4; all 8 waves read the same 32 KB -> L1-served.
  short8 a[2][16];
  {
    const unsigned short* ysrc = yPack + (size_t)blk * (32 * 512);
#pragma unroll
    for (int mt = 0; mt < 2; ++mt)
#pragma unroll
      for (int ks = 0; ks < 16; ++ks)
        a[mt][ks] = *(const short8*)&ysrc[((mt * 16 + ks) * 64 + lane) * 8];
  }

  floatx4 accY[2][4] = {};  // [mt][i], cols w*64 + i*16 + l15

  for (int c = 0; c < NCH; ++c) {
    // ---- phase1: h[:, c*CW + (w*2..w*2+1)*16] = tanh(y @ W1-slice + b1) ----
    floatx4 acc1[2][2] = {};  // [i1][mt]
    const int nbBase = c * 16 + w * 2;  // H col-tile 0..127
#pragma unroll
    for (int ks = 0; ks < 16; ++ks) {
      short8 b0 = *(const short8*)&w1p[((size_t)((nbBase + 0) * 16 + ks) * 64 + lane) * 8];
      short8 b1v = *(const short8*)&w1p[((size_t)((nbBase + 1) * 16 + ks) * 64 + lane) * 8];
      acc1[0][0] = __builtin_amdgcn_mfma_f32_16x16x32_bf16(a[0][ks], b0, acc1[0][0], 0, 0, 0);
      acc1[0][1] = __builtin_amdgcn_mfma_f32_16x16x32_bf16(a[1][ks], b0, acc1[0][1], 0, 0, 0);
      acc1[1][0] = __builtin_amdgcn_mfma_f32_16x16x32_bf16(a[0][ks], b1v, acc1[1][0], 0, 0, 0);
      acc1[1][1] = __builtin_amdgcn_mfma_f32_16x16x32_bf16(a[1][ks], b1v, acc1[1][1], 0, 0, 0);
    }
    // bias + tanh + scatter into hA[c&1] in A-frag layout (k = h-col in chunk)
    {
      unsigned short* hbuf = hA[c & 1];
#pragma unroll
      for (int i1 = 0; i1 < 2; ++i1) {
        const int kloc = (w * 2 + i1) * 16 + l15;   // 0..255 (this lane's h-col)
        const float bb = b1[c * CW + kloc];
        const int ksa = kloc >> 5;
        const int qa  = (kloc & 31) >> 3;
        const int kb7 = kloc & 7;
#pragma unroll
        for (int mt = 0; mt < 2; ++mt)
#pragma unroll
          for (int r = 0; r < 4; ++r) {
            const int m15 = quad * 4 + r;           // C row -> A-frag m
            hbuf[((mt * 8 + ksa) * 64 + qa * 16 + m15) * 8 + kb7] =
                f2bf(fast_tanh(acc1[i1][mt][r] + bb));
          }
      }
    }
    // ---- phase2 for chunk c-1: accY += h_prev @ W2-slice ----
    if (c > 0) {
      const unsigned short* hprev = hA[(c - 1) & 1];
      const int kb0 = (c - 1) * 8;
#pragma unroll
      for (int ks = 0; ks < 8; ++ks) {
        short8 ha0 = *(const short8*)&hprev[((0 * 8 + ks) * 64 + lane) * 8];
        short8 ha1 = *(const short8*)&hprev[((1 * 8 + ks) * 64 + lane) * 8];
#pragma unroll
        for (int i = 0; i < 4; ++i) {
          const int nb2 = w * 4 + i;                // D col-tile 0..31
          short8 b = *(const short8*)&w2p[((size_t)(nb2 * 64 + kb0 + ks) * 64 + lane) * 8];
          accY[0][i] = __builtin_amdgcn_mfma_f32_16x16x32_bf16(ha0, b, accY[0][i], 0, 0, 0);
          accY[1][i] = __builtin_amdgcn_mfma_f32_16x16x32_bf16(ha1, b, accY[1][i], 0, 0, 0);
        }
      }
    }
    __syncthreads();
  }
  // tail phase2: chunk NCH-1 (buffer (NCH-1)&1 = 1)
  {
    const unsigned short* hprev = hA[(NCH - 1) & 1];
    const int kb0 = (NCH - 1) * 8;
#pragma unroll
    for (int ks = 0; ks < 8; ++ks) {
      short8 ha0 = *(const short8*)&hprev[((0 * 8 + ks) * 64 + lane) * 8];
      short8 ha1 = *(const short8*)&hprev[((1 * 8 + ks) * 64 + lane) * 8];
#pragma unroll
      for (int i = 0; i < 4; ++i) {
        const int nb2 = w * 4 + i;
        short8 b = *(const short8*)&w2p[((size_t)(nb2 * 64 + kb0 + ks) * 64 + lane) * 8];
        accY[0][i] = __builtin_amdgcn_mfma_f32_16x16x32_bf16(ha0, b, accY[0][i], 0, 0, 0);
        accY[1][i] = __builtin_amdgcn_mfma_f32_16x16x32_bf16(ha1, b, accY[1][i], 0, 0, 0);
      }
    }
  }
  __syncthreads();  // all waves done reading hA before reuse as pack staging

  // Epilogue: add b2, Heun combine with fp32 state, pack bf16 result.
  {
    unsigned short* pbuf = &hA[0][0];  // 32 KB staging, yPack layout (mt*16+ksa)
#pragma unroll
    for (int i = 0; i < 4; ++i) {
      const int ncol = w * 64 + i * 16 + l15;  // 0..511
      const float bb = b2[ncol];
      const int ksa = ncol >> 5;
      const int qa  = (ncol & 31) >> 3;
      const int nb7 = ncol & 7;
#pragma unroll
      for (int mt = 0; mt < 2; ++mt)
#pragma unroll
        for (int r = 0; r < 4; ++r) {
          const int row = B0 + mt * 16 + quad * 4 + r;
          const size_t idx = (size_t)row * DDIM + ncol;
          const float v = accY[mt][i][r] + bb;
          float nv;
          if (epi == 1) {
            const float y = stateIn[idx];
            stateOut[idx] = y + 0.05f * v;   // p = y + (dt/2)*k1
            nv = y + 0.1f * v;               // ymid
          } else {
            const float yn = stateIn[idx] + 0.05f * v;  // ynew = p + (dt/2)*k2
            stateOut[idx] = yn;
            nv = yn;
          }
          const int m15 = quad * 4 + r;
          pbuf[((mt * 16 + ksa) * 64 + qa * 16 + m15) * 8 + nb7] = f2bf(nv);
        }
    }
    __syncthreads();
    unsigned short* dst = outPack + (size_t)blk * (32 * 512);
#pragma unroll
    for (int p = 0; p < 4; ++p) {
      short8 v = *(const short8*)&pbuf[(size_t)(p * 512 + tid) * 8];
      *(short8*)&dst[(size_t)(p * 512 + tid) * 8] = v;
    }
  }
}

// Pack weight [K][N] fp32 -> B-frag order: frag f = nb*KB + kb,
// lane entry = src[kb*32 + quad*8 + j][nb*16 + l15].
__global__ void pack_b(const float* __restrict__ src, unsigned short* __restrict__ dst,
                       int KB, int N) {
  const int t = blockIdx.x * 256 + threadIdx.x;
  const int lane = t & 63, f = t >> 6;
  const int nb = f / KB, kb = f % KB;
  const int quad = lane >> 4, l15 = lane & 15;
  const int k0 = kb * 32 + quad * 8, n = nb * 16 + l15;
  short8 v;
#pragma unroll
  for (int j = 0; j < 8; ++j)
    v[j] = (short)f2bf(src[(size_t)(k0 + j) * N + n]);
  *(short8*)&dst[(size_t)t * 8] = v;
}

// y0 fp32 [8192][512] -> yF fp32 copy + packed bf16 A-frags.
__global__ void pack_y(const float* __restrict__ y0, float* __restrict__ yF,
                       unsigned short* __restrict__ ypk) {
  const int t = blockIdx.x * 256 + threadIdx.x;
  const int lane = t & 63, f = t >> 6;
  const int rb = f >> 4, ks = f & 15;
  const int quad = lane >> 4, l15 = lane & 15;
  const int row = rb * 16 + l15, c0 = ks * 32 + quad * 8;
  short8 v;
#pragma unroll
  for (int j = 0; j < 8; ++j) {
    const float x = y0[(size_t)row * DDIM + c0 + j];
    yF[(size_t)row * DDIM + c0 + j] = x;
    v[j] = (short)f2bf(x);
  }
  *(short8*)&ypk[(size_t)t * 8] = v;
}

extern "C" void kernel_launch(void* const* d_in, const int* in_sizes, int n_in,
                              void* d_out, int out_size, void* d_ws, size_t ws_size,
                              hipStream_t stream) {
  const float* y0 = (const float*)d_in[0];
  const float* W1 = (const float*)d_in[1];  // [512][2048]
  const float* b1 = (const float*)d_in[2];  // [2048]
  const float* W2 = (const float*)d_in[3];  // [2048][512]
  const float* b2 = (const float*)d_in[4];  // [512]

  char* ws = (char*)d_ws;
  float*          yF   = (float*)(ws);                         // 16 MB
  float*          pF   = (float*)(ws + (size_t)(16u << 20));   // 16 MB
  unsigned short* ypk  = (unsigned short*)(ws + (size_t)(32u << 20)); // 8 MB
  unsigned short* ympk = (unsigned short*)(ws + (size_t)(40u << 20)); // 8 MB
  unsigned short* w1p  = (unsigned short*)(ws + (size_t)(48u << 20)); // 2 MB
  unsigned short* w2p  = (unsigned short*)(ws + (size_t)(50u << 20)); // 2 MB

  // Pre-pass: pack weights (2048 frags each) and y0 (8192 frags).
  pack_b<<<512, 256, 0, stream>>>(W1, w1p, 16, HDIM);
  pack_b<<<512, 256, 0, stream>>>(W2, w2p, 64, DDIM);
  pack_y<<<2048, 256, 0, stream>>>(y0, yF, ypk);

  const dim3 grid(256), blkd(512);
  for (int s = 0; s < 10; ++s) {
    // eval1: k1 = f(y); p = y + 0.05*k1; ymid = y + 0.1*k1 (packed)
    fused_feval<<<grid, blkd, 0, stream>>>(ypk, w1p, w2p, b1, b2, yF, pF, ympk, 1);
    // eval2: k2 = f(ymid); ynew = p + 0.05*k2 (fp32 + packed)
    float* yOut = (s == 9) ? (float*)d_out : yF;
    fused_feval<<<grid, blkd, 0, stream>>>(ympk, w1p, w2p, b1, b2, pF, yOut, ypk, 2);
  }
}

// Round 3
// 1700.396 us; speedup vs baseline: 1.3282x; 1.3282x over previous
//
#include <hip/hip_runtime.h>
#include <hip/hip_bf16.h>
#include <cstdint>

// Neural ODE: 10 Heun steps of f(y) = tanh(y@W1 + b1)@W2 + b2
// BATCH=8192, D=512, H=2048, dt=0.1
// R8 (resubmit R9 — prior round was an infra failure, kernel unchanged):
// R6 structure (16 waves, LDS-staged A — proven 66.5us) with CW=512
// (NCH=4) and 2 GEMM1 n-tiles per wave. Each yA ds_read_b128 now feeds 4
// MFMAs instead of 2 -> GEMM1 LDS A-traffic halves (4MB->2MB/block/eval),
// LDS pipe ~balanced with MFMA issue. Single-buffered hA keeps LDS at 64KB;
// 2 barriers/chunk x 4 chunks = same 8 barriers as R6, with a bigger
// overlap window (phase2(c) + phase1(c+1)) between barrier pairs.
// R7 lesson: register-resident A remats to global reloads (VGPR cap 128),
// never again.

#define BATCHN 8192
#define DDIM 512
#define HDIM 2048
#define CW 512          // chunk width over H
#define NCH (HDIM / CW) // 4

typedef short short8 __attribute__((ext_vector_type(8)));
typedef float floatx4 __attribute__((ext_vector_type(4)));

__device__ __forceinline__ unsigned short f2bf(float f) {
  union { __hip_bfloat16 h; unsigned short u; } cv;
  cv.h = __float2bfloat16(f);
  return cv.u;
}

__device__ __forceinline__ float fast_tanh(float x) {
  float e = __expf(2.0f * x);
  return 1.0f - 2.0f / (e + 1.0f);
}

__device__ __forceinline__ void glds16(const void* g, void* l) {
  __builtin_amdgcn_global_load_lds(
      (const __attribute__((address_space(1))) void*)(uintptr_t)g,
      (__attribute__((address_space(3))) void*)(uint32_t)(uintptr_t)l,
      16, 0, 0);
}

// Fragment conventions (verified by R1-R6 passing kernels):
//  A-frag (16x16x32): lane holds A[m = l15][k = quad*8 + j], j=0..7 (16B)
//  B-frag:            lane holds B[n = l15][k = quad*8 + j]  (BT row-major)
//  C/D:               row = quad*4 + r, col = l15
// Packed buffers: frag f stored at [(f*64 + lane)*8] halves.
//  yPack: f = rb*16 + ks   (rb = batch-row/16: 0..511, ks = D k-step: 0..15)
//  w1p:   f = nb*16 + kb   (nb = H col-tile: 0..127,   kb = D k-step: 0..15)
//  w2p:   f = nb*64 + kb   (nb = D col-tile: 0..31,    kb = H k-step: 0..63)

__global__ __launch_bounds__(1024, 4) void fused_feval(
    const unsigned short* __restrict__ yPack,   // packed bf16 eval input
    const unsigned short* __restrict__ w1p,
    const unsigned short* __restrict__ w2p,
    const float* __restrict__ b1,
    const float* __restrict__ b2,
    const float* __restrict__ stateIn,   // EPI1: y fp32 ; EPI2: p fp32
    float* __restrict__ stateOut,        // EPI1: p      ; EPI2: ynew
    unsigned short* __restrict__ outPack,// packed bf16 next-eval input
    int epi) {                           // 1 or 2
  __shared__ unsigned short yA[32 * 512];   // 32 KB, frag (mt*16+ks)
  __shared__ unsigned short hA[32 * CW];    // 32 KB single buffer, frag (mt*16+ks)

  const int tid  = threadIdx.x;
  const int lane = tid & 63;
  const int w    = tid >> 6;    // wave 0..15
  const int quad = lane >> 4;
  const int l15  = lane & 15;
  const int blk  = blockIdx.x;  // 0..255
  const int B0   = blk * 32;    // slab base row

  // phase0: linear copy of this block's 32 KB packed y-slab into LDS.
  {
    const unsigned short* src = yPack + (size_t)blk * (32 * 512);
    glds16(src + (size_t)tid * 8, &yA[tid * 8]);
    glds16(src + (size_t)(1024 + tid) * 8, &yA[(1024 + tid) * 8]);
  }
  __syncthreads();

  floatx4 accY[2][2] = {};  // [mt][i], cols w*32 + i*16 + l15

  for (int c = 0; c < NCH; ++c) {
    // ---- phase1: acc1 = y @ W1[:, c*CW + (w*2+{0,1})*16 ..] ----
    // No hA access here: this compute sits in the overlap window with
    // phase2(c-1) from the previous iteration.
    floatx4 acc1[2][2] = {};  // [i1][mt]
    const int nbB = c * 32 + w * 2;  // H col-tile 0..127
#pragma unroll
    for (int ks = 0; ks < 16; ++ks) {
      short8 a0  = *(const short8*)&yA[((0 * 16 + ks) * 64 + lane) * 8];
      short8 a1  = *(const short8*)&yA[((1 * 16 + ks) * 64 + lane) * 8];
      short8 b0  = *(const short8*)&w1p[((size_t)((nbB + 0) * 16 + ks) * 64 + lane) * 8];
      short8 b1v = *(const short8*)&w1p[((size_t)((nbB + 1) * 16 + ks) * 64 + lane) * 8];
      acc1[0][0] = __builtin_amdgcn_mfma_f32_16x16x32_bf16(a0, b0, acc1[0][0], 0, 0, 0);
      acc1[0][1] = __builtin_amdgcn_mfma_f32_16x16x32_bf16(a1, b0, acc1[0][1], 0, 0, 0);
      acc1[1][0] = __builtin_amdgcn_mfma_f32_16x16x32_bf16(a0, b1v, acc1[1][0], 0, 0, 0);
      acc1[1][1] = __builtin_amdgcn_mfma_f32_16x16x32_bf16(a1, b1v, acc1[1][1], 0, 0, 0);
    }
    __syncthreads();  // all waves done READING hA (phase2 of chunk c-1)
    // bias + tanh + scatter into hA in A-frag layout (k = h-col in chunk)
    {
#pragma unroll
      for (int i1 = 0; i1 < 2; ++i1) {
        const int kloc = (w * 2 + i1) * 16 + l15;   // 0..511 (lane's h-col)
        const float bb = b1[c * CW + kloc];
        const int ksa = kloc >> 5;                  // 0..15
        const int qa  = (kloc & 31) >> 3;
        const int kb7 = kloc & 7;
#pragma unroll
        for (int mt = 0; mt < 2; ++mt)
#pragma unroll
          for (int r = 0; r < 4; ++r) {
            const int m15 = quad * 4 + r;           // C row -> A-frag m
            hA[((mt * 16 + ksa) * 64 + qa * 16 + m15) * 8 + kb7] =
                f2bf(fast_tanh(acc1[i1][mt][r] + bb));
          }
      }
    }
    __syncthreads();  // hA(c) visible to all waves
    // ---- phase2: accY += h(c) @ W2[c*CW .. , :] ----
#pragma unroll
    for (int ks = 0; ks < 16; ++ks) {
      short8 ha0 = *(const short8*)&hA[((0 * 16 + ks) * 64 + lane) * 8];
      short8 ha1 = *(const short8*)&hA[((1 * 16 + ks) * 64 + lane) * 8];
#pragma unroll
      for (int i = 0; i < 2; ++i) {
        const int nb2 = w * 2 + i;                  // D col-tile 0..31
        short8 b = *(const short8*)&w2p[((size_t)(nb2 * 64 + c * 16 + ks) * 64 + lane) * 8];
        accY[0][i] = __builtin_amdgcn_mfma_f32_16x16x32_bf16(ha0, b, accY[0][i], 0, 0, 0);
        accY[1][i] = __builtin_amdgcn_mfma_f32_16x16x32_bf16(ha1, b, accY[1][i], 0, 0, 0);
      }
    }
  }
  __syncthreads();  // all waves done reading hA before reuse as pack staging

  // Epilogue: add b2, Heun combine with fp32 state, pack bf16 result.
  {
    unsigned short* pbuf = &hA[0];  // 32 KB staging, yPack layout (mt*16+ksa)
#pragma unroll
    for (int i = 0; i < 2; ++i) {
      const int ncol = w * 32 + i * 16 + l15;  // 0..511
      const float bb = b2[ncol];
      const int ksa = ncol >> 5;
      const int qa  = (ncol & 31) >> 3;
      const int nb7 = ncol & 7;
#pragma unroll
      for (int mt = 0; mt < 2; ++mt)
#pragma unroll
        for (int r = 0; r < 4; ++r) {
          const int row = B0 + mt * 16 + quad * 4 + r;
          const size_t idx = (size_t)row * DDIM + ncol;
          const float v = accY[mt][i][r] + bb;
          float nv;
          if (epi == 1) {
            const float y = stateIn[idx];
            stateOut[idx] = y + 0.05f * v;   // p = y + (dt/2)*k1
            nv = y + 0.1f * v;               // ymid
          } else {
            const float yn = stateIn[idx] + 0.05f * v;  // ynew = p + (dt/2)*k2
            stateOut[idx] = yn;
            nv = yn;
          }
          const int m15 = quad * 4 + r;
          pbuf[((mt * 16 + ksa) * 64 + qa * 16 + m15) * 8 + nb7] = f2bf(nv);
        }
    }
    __syncthreads();
    unsigned short* dst = outPack + (size_t)blk * (32 * 512);
#pragma unroll
    for (int p = 0; p < 2; ++p) {
      short8 v = *(const short8*)&pbuf[(size_t)(p * 1024 + tid) * 8];
      *(short8*)&dst[(size_t)(p * 1024 + tid) * 8] = v;
    }
  }
}

// Pack weight [K][N] fp32 -> B-frag order: frag f = nb*KB + kb,
// lane entry = src[kb*32 + quad*8 + j][nb*16 + l15].
__global__ void pack_b(const float* __restrict__ src, unsigned short* __restrict__ dst,
                       int KB, int N) {
  const int t = blockIdx.x * 256 + threadIdx.x;
  const int lane = t & 63, f = t >> 6;
  const int nb = f / KB, kb = f % KB;
  const int quad = lane >> 4, l15 = lane & 15;
  const int k0 = kb * 32 + quad * 8, n = nb * 16 + l15;
  short8 v;
#pragma unroll
  for (int j = 0; j < 8; ++j)
    v[j] = (short)f2bf(src[(size_t)(k0 + j) * N + n]);
  *(short8*)&dst[(size_t)t * 8] = v;
}

// y0 fp32 [8192][512] -> yF fp32 copy + packed bf16 A-frags.
__global__ void pack_y(const float* __restrict__ y0, float* __restrict__ yF,
                       unsigned short* __restrict__ ypk) {
  const int t = blockIdx.x * 256 + threadIdx.x;
  const int lane = t & 63, f = t >> 6;
  const int rb = f >> 4, ks = f & 15;
  const int quad = lane >> 4, l15 = lane & 15;
  const int row = rb * 16 + l15, c0 = ks * 32 + quad * 8;
  short8 v;
#pragma unroll
  for (int j = 0; j < 8; ++j) {
    const float x = y0[(size_t)row * DDIM + c0 + j];
    yF[(size_t)row * DDIM + c0 + j] = x;
    v[j] = (short)f2bf(x);
  }
  *(short8*)&ypk[(size_t)t * 8] = v;
}

extern "C" void kernel_launch(void* const* d_in, const int* in_sizes, int n_in,
                              void* d_out, int out_size, void* d_ws, size_t ws_size,
                              hipStream_t stream) {
  const float* y0 = (const float*)d_in[0];
  const float* W1 = (const float*)d_in[1];  // [512][2048]
  const float* b1 = (const float*)d_in[2];  // [2048]
  const float* W2 = (const float*)d_in[3];  // [2048][512]
  const float* b2 = (const float*)d_in[4];  // [512]

  char* ws = (char*)d_ws;
  float*          yF   = (float*)(ws);                         // 16 MB
  float*          pF   = (float*)(ws + (size_t)(16u << 20));   // 16 MB
  unsigned short* ypk  = (unsigned short*)(ws + (size_t)(32u << 20)); // 8 MB
  unsigned short* ympk = (unsigned short*)(ws + (size_t)(40u << 20)); // 8 MB
  unsigned short* w1p  = (unsigned short*)(ws + (size_t)(48u << 20)); // 2 MB
  unsigned short* w2p  = (unsigned short*)(ws + (size_t)(50u << 20)); // 2 MB

  // Pre-pass: pack weights (2048 frags each) and y0 (8192 frags).
  pack_b<<<512, 256, 0, stream>>>(W1, w1p, 16, HDIM);
  pack_b<<<512, 256, 0, stream>>>(W2, w2p, 64, DDIM);
  pack_y<<<2048, 256, 0, stream>>>(y0, yF, ypk);

  const dim3 grid(256), blkd(1024);
  for (int s = 0; s < 10; ++s) {
    // eval1: k1 = f(y); p = y + 0.05*k1; ymid = y + 0.1*k1 (packed)
    fused_feval<<<grid, blkd, 0, stream>>>(ypk, w1p, w2p, b1, b2, yF, pF, ympk, 1);
    // eval2: k2 = f(ymid); ynew = p + 0.05*k2 (fp32 + packed)
    float* yOut = (s == 9) ? (float*)d_out : yF;
    fused_feval<<<grid, blkd, 0, stream>>>(ympk, w1p, w2p, b1, b2, pF, yOut, ypk, 2);
  }
}

// Round 4
// 1510.150 us; speedup vs baseline: 1.4955x; 1.1260x over previous
//
#include <hip/hip_runtime.h>
#include <hip/hip_bf16.h>
#include <cstdint>

// Neural ODE: 10 Heun steps of f(y) = tanh(y@W1 + b1)@W2 + b2
// BATCH=8192, D=512, H=2048, dt=0.1
// R10: R6's proven overlap schedule (ONE barrier per chunk; double-buffered
// hA; phase1(c) + scatter(c) + phase2(c-1) share one window) with CW=512.
// hA 2x32KB + yA 32KB = 96KB LDS (1 block/CU, fits 160KB). Each wave takes
// 2 GEMM1 n-tiles -> every yA ds_read_b128 feeds 4 MFMAs; per-wave LDS reads
// 384->256 b128/eval; chunks 8->4 halves barrier count and per-barrier L2
// latency exposure.
// R7 lesson: register-resident A remats to global reloads. R8 lesson: the
// two-barrier/serialized-scatter structure costs +29% — never serialize the
// scatter outside an MFMA overlap window.

#define BATCHN 8192
#define DDIM 512
#define HDIM 2048
#define CW 512          // chunk width over H
#define NCH (HDIM / CW) // 4

typedef short short8 __attribute__((ext_vector_type(8)));
typedef float floatx4 __attribute__((ext_vector_type(4)));

__device__ __forceinline__ unsigned short f2bf(float f) {
  union { __hip_bfloat16 h; unsigned short u; } cv;
  cv.h = __float2bfloat16(f);
  return cv.u;
}

__device__ __forceinline__ float fast_tanh(float x) {
  float e = __expf(2.0f * x);
  return 1.0f - 2.0f / (e + 1.0f);
}

__device__ __forceinline__ void glds16(const void* g, void* l) {
  __builtin_amdgcn_global_load_lds(
      (const __attribute__((address_space(1))) void*)(uintptr_t)g,
      (__attribute__((address_space(3))) void*)(uint32_t)(uintptr_t)l,
      16, 0, 0);
}

// Fragment conventions (verified by R1-R6 passing kernels):
//  A-frag (16x16x32): lane holds A[m = l15][k = quad*8 + j], j=0..7 (16B)
//  B-frag:            lane holds B[n = l15][k = quad*8 + j]  (BT row-major)
//  C/D:               row = quad*4 + r, col = l15
// Packed buffers: frag f stored at [(f*64 + lane)*8] halves.
//  yPack: f = rb*16 + ks   (rb = batch-row/16: 0..511, ks = D k-step: 0..15)
//  w1p:   f = nb*16 + kb   (nb = H col-tile: 0..127,   kb = D k-step: 0..15)
//  w2p:   f = nb*64 + kb   (nb = D col-tile: 0..31,    kb = H k-step: 0..63)

__global__ __launch_bounds__(1024, 4) void fused_feval(
    const unsigned short* __restrict__ yPack,   // packed bf16 eval input
    const unsigned short* __restrict__ w1p,
    const unsigned short* __restrict__ w2p,
    const float* __restrict__ b1,
    const float* __restrict__ b2,
    const float* __restrict__ stateIn,   // EPI1: y fp32 ; EPI2: p fp32
    float* __restrict__ stateOut,        // EPI1: p      ; EPI2: ynew
    unsigned short* __restrict__ outPack,// packed bf16 next-eval input
    int epi) {                           // 1 or 2
  __shared__ unsigned short yA[32 * 512];       // 32 KB, frag (mt*16+ks)
  __shared__ unsigned short hA[2][32 * CW];     // 2 x 32 KB, frag (mt*16+ks)

  const int tid  = threadIdx.x;
  const int lane = tid & 63;
  const int w    = tid >> 6;    // wave 0..15
  const int quad = lane >> 4;
  const int l15  = lane & 15;
  const int blk  = blockIdx.x;  // 0..255
  const int B0   = blk * 32;    // slab base row

  // phase0: linear copy of this block's 32 KB packed y-slab into LDS.
  {
    const unsigned short* src = yPack + (size_t)blk * (32 * 512);
    glds16(src + (size_t)tid * 8, &yA[tid * 8]);
    glds16(src + (size_t)(1024 + tid) * 8, &yA[(1024 + tid) * 8]);
  }
  __syncthreads();

  floatx4 accY[2][2] = {};  // [mt][i], cols w*32 + i*16 + l15

  for (int c = 0; c < NCH; ++c) {
    // ---- phase1: acc1 = y @ W1[:, c*CW + (w*2+{0,1})*16 ..] ----
    floatx4 acc1[2][2] = {};  // [i1][mt]
    const int nbB = c * 32 + w * 2;  // H col-tile 0..127
#pragma unroll
    for (int ks = 0; ks < 16; ++ks) {
      short8 a0  = *(const short8*)&yA[((0 * 16 + ks) * 64 + lane) * 8];
      short8 a1  = *(const short8*)&yA[((1 * 16 + ks) * 64 + lane) * 8];
      short8 b0  = *(const short8*)&w1p[((size_t)((nbB + 0) * 16 + ks) * 64 + lane) * 8];
      short8 b1v = *(const short8*)&w1p[((size_t)((nbB + 1) * 16 + ks) * 64 + lane) * 8];
      acc1[0][0] = __builtin_amdgcn_mfma_f32_16x16x32_bf16(a0, b0, acc1[0][0], 0, 0, 0);
      acc1[0][1] = __builtin_amdgcn_mfma_f32_16x16x32_bf16(a1, b0, acc1[0][1], 0, 0, 0);
      acc1[1][0] = __builtin_amdgcn_mfma_f32_16x16x32_bf16(a0, b1v, acc1[1][0], 0, 0, 0);
      acc1[1][1] = __builtin_amdgcn_mfma_f32_16x16x32_bf16(a1, b1v, acc1[1][1], 0, 0, 0);
    }
    // bias + tanh + scatter into hA[c&1] in A-frag layout (k = h-col in chunk)
    {
      unsigned short* hbuf = hA[c & 1];
#pragma unroll
      for (int i1 = 0; i1 < 2; ++i1) {
        const int kloc = (w * 2 + i1) * 16 + l15;   // 0..511 (lane's h-col)
        const float bb = b1[c * CW + kloc];
        const int ksa = kloc >> 5;                  // 0..15
        const int qa  = (kloc & 31) >> 3;
        const int kb7 = kloc & 7;
#pragma unroll
        for (int mt = 0; mt < 2; ++mt)
#pragma unroll
          for (int r = 0; r < 4; ++r) {
            const int m15 = quad * 4 + r;           // C row -> A-frag m
            hbuf[((mt * 16 + ksa) * 64 + qa * 16 + m15) * 8 + kb7] =
                f2bf(fast_tanh(acc1[i1][mt][r] + bb));
          }
      }
    }
    // ---- phase2 for chunk c-1: accY += h_prev @ W2-slice ----
    if (c > 0) {
      const unsigned short* hprev = hA[(c - 1) & 1];
      const int kb0 = (c - 1) * 16;
#pragma unroll
      for (int ks = 0; ks < 16; ++ks) {
        short8 ha0 = *(const short8*)&hprev[((0 * 16 + ks) * 64 + lane) * 8];
        short8 ha1 = *(const short8*)&hprev[((1 * 16 + ks) * 64 + lane) * 8];
#pragma unroll
        for (int i = 0; i < 2; ++i) {
          const int nb2 = w * 2 + i;                // D col-tile 0..31
          short8 b = *(const short8*)&w2p[((size_t)(nb2 * 64 + kb0 + ks) * 64 + lane) * 8];
          accY[0][i] = __builtin_amdgcn_mfma_f32_16x16x32_bf16(ha0, b, accY[0][i], 0, 0, 0);
          accY[1][i] = __builtin_amdgcn_mfma_f32_16x16x32_bf16(ha1, b, accY[1][i], 0, 0, 0);
        }
      }
    }
    __syncthreads();
  }
  // tail phase2: chunk NCH-1 (buffer (NCH-1)&1 = 1)
  {
    const unsigned short* hprev = hA[(NCH - 1) & 1];
    const int kb0 = (NCH - 1) * 16;
#pragma unroll
    for (int ks = 0; ks < 16; ++ks) {
      short8 ha0 = *(const short8*)&hprev[((0 * 16 + ks) * 64 + lane) * 8];
      short8 ha1 = *(const short8*)&hprev[((1 * 16 + ks) * 64 + lane) * 8];
#pragma unroll
      for (int i = 0; i < 2; ++i) {
        const int nb2 = w * 2 + i;
        short8 b = *(const short8*)&w2p[((size_t)(nb2 * 64 + kb0 + ks) * 64 + lane) * 8];
        accY[0][i] = __builtin_amdgcn_mfma_f32_16x16x32_bf16(ha0, b, accY[0][i], 0, 0, 0);
        accY[1][i] = __builtin_amdgcn_mfma_f32_16x16x32_bf16(ha1, b, accY[1][i], 0, 0, 0);
      }
    }
  }
  __syncthreads();  // all waves done reading hA before reuse as pack staging

  // Epilogue: add b2, Heun combine with fp32 state, pack bf16 result.
  {
    unsigned short* pbuf = &hA[0][0];  // 32 KB staging, yPack layout (mt*16+ksa)
#pragma unroll
    for (int i = 0; i < 2; ++i) {
      const int ncol = w * 32 + i * 16 + l15;  // 0..511
      const float bb = b2[ncol];
      const int ksa = ncol >> 5;
      const int qa  = (ncol & 31) >> 3;
      const int nb7 = ncol & 7;
#pragma unroll
      for (int mt = 0; mt < 2; ++mt)
#pragma unroll
        for (int r = 0; r < 4; ++r) {
          const int row = B0 + mt * 16 + quad * 4 + r;
          const size_t idx = (size_t)row * DDIM + ncol;
          const float v = accY[mt][i][r] + bb;
          float nv;
          if (epi == 1) {
            const float y = stateIn[idx];
            stateOut[idx] = y + 0.05f * v;   // p = y + (dt/2)*k1
            nv = y + 0.1f * v;               // ymid
          } else {
            const float yn = stateIn[idx] + 0.05f * v;  // ynew = p + (dt/2)*k2
            stateOut[idx] = yn;
            nv = yn;
          }
          const int m15 = quad * 4 + r;
          pbuf[((mt * 16 + ksa) * 64 + qa * 16 + m15) * 8 + nb7] = f2bf(nv);
        }
    }
    __syncthreads();
    unsigned short* dst = outPack + (size_t)blk * (32 * 512);
#pragma unroll
    for (int p = 0; p < 2; ++p) {
      short8 v = *(const short8*)&pbuf[(size_t)(p * 1024 + tid) * 8];
      *(short8*)&dst[(size_t)(p * 1024 + tid) * 8] = v;
    }
  }
}

// Pack weight [K][N] fp32 -> B-frag order: frag f = nb*KB + kb,
// lane entry = src[kb*32 + quad*8 + j][nb*16 + l15].
__global__ void pack_b(const float* __restrict__ src, unsigned short* __restrict__ dst,
                       int KB, int N) {
  const int t = blockIdx.x * 256 + threadIdx.x;
  const int lane = t & 63, f = t >> 6;
  const int nb = f / KB, kb = f % KB;
  const int quad = lane >> 4, l15 = lane & 15;
  const int k0 = kb * 32 + quad * 8, n = nb * 16 + l15;
  short8 v;
#pragma unroll
  for (int j = 0; j < 8; ++j)
    v[j] = (short)f2bf(src[(size_t)(k0 + j) * N + n]);
  *(short8*)&dst[(size_t)t * 8] = v;
}

// y0 fp32 [8192][512] -> yF fp32 copy + packed bf16 A-frags.
__global__ void pack_y(const float* __restrict__ y0, float* __restrict__ yF,
                       unsigned short* __restrict__ ypk) {
  const int t = blockIdx.x * 256 + threadIdx.x;
  const int lane = t & 63, f = t >> 6;
  const int rb = f >> 4, ks = f & 15;
  const int quad = lane >> 4, l15 = lane & 15;
  const int row = rb * 16 + l15, c0 = ks * 32 + quad * 8;
  short8 v;
#pragma unroll
  for (int j = 0; j < 8; ++j) {
    const float x = y0[(size_t)row * DDIM + c0 + j];
    yF[(size_t)row * DDIM + c0 + j] = x;
    v[j] = (short)f2bf(x);
  }
  *(short8*)&ypk[(size_t)t * 8] = v;
}

extern "C" void kernel_launch(void* const* d_in, const int* in_sizes, int n_in,
                              void* d_out, int out_size, void* d_ws, size_t ws_size,
                              hipStream_t stream) {
  const float* y0 = (const float*)d_in[0];
  const float* W1 = (const float*)d_in[1];  // [512][2048]
  const float* b1 = (const float*)d_in[2];  // [2048]
  const float* W2 = (const float*)d_in[3];  // [2048][512]
  const float* b2 = (const float*)d_in[4];  // [512]

  char* ws = (char*)d_ws;
  float*          yF   = (float*)(ws);                         // 16 MB
  float*          pF   = (float*)(ws + (size_t)(16u << 20));   // 16 MB
  unsigned short* ypk  = (unsigned short*)(ws + (size_t)(32u << 20)); // 8 MB
  unsigned short* ympk = (unsigned short*)(ws + (size_t)(40u << 20)); // 8 MB
  unsigned short* w1p  = (unsigned short*)(ws + (size_t)(48u << 20)); // 2 MB
  unsigned short* w2p  = (unsigned short*)(ws + (size_t)(50u << 20)); // 2 MB

  // Pre-pass: pack weights (2048 frags each) and y0 (8192 frags).
  pack_b<<<512, 256, 0, stream>>>(W1, w1p, 16, HDIM);
  pack_b<<<512, 256, 0, stream>>>(W2, w2p, 64, DDIM);
  pack_y<<<2048, 256, 0, stream>>>(y0, yF, ypk);

  const dim3 grid(256), blkd(1024);
  for (int s = 0; s < 10; ++s) {
    // eval1: k1 = f(y); p = y + 0.05*k1; ymid = y + 0.1*k1 (packed)
    fused_feval<<<grid, blkd, 0, stream>>>(ypk, w1p, w2p, b1, b2, yF, pF, ympk, 1);
    // eval2: k2 = f(ymid); ynew = p + 0.05*k2 (fp32 + packed)
    float* yOut = (s == 9) ? (float*)d_out : yF;
    fused_feval<<<grid, blkd, 0, stream>>>(ympk, w1p, w2p, b1, b2, pF, yOut, ypk, 2);
  }
}

// Round 5
// 1190.640 us; speedup vs baseline: 1.8968x; 1.2684x over previous
//
#include <hip/hip_runtime.h>
#include <hip/hip_bf16.h>
#include <cstdint>

// Neural ODE: 10 Heun steps of f(y) = tanh(y@W1 + b1)@W2 + b2
// BATCH=8192, D=512, H=2048, dt=0.1
// R11 = R6 (proven 66.5us/eval) + vmem software pipelining ONLY:
//  - rotating next-iter register prefetch of W1/W2 B-frags (the only global
//    loads in the hot loops); A-side ds_reads stay JIT (compiler handles
//    lgkmcnt fine-grained per m97 evidence).
//  - phase2's first B-pair issued BEFORE the tanh scatter (~500 VALU cyc)
//    so its L2 latency hides under VALU.
//  - chunk loop fully unrolled; per-chunk b1 biases preloaded to registers.
// Counter model for R6: LDS pipe ~31us + L2 weight stream ~30us SERIALIZED
// (sum ~= measured 66.5; MfmaUtil 20% = 13.7us MFMA floor). This round
// overlaps the two memory pipes within each wave.
// Dead axes: R7 reg-resident A (remats), R8/R10 CW=512 (regressed, cause
// unexplained — axis frozen).

#define BATCHN 8192
#define DDIM 512
#define HDIM 2048
#define CW 256          // chunk width over H
#define NCH (HDIM / CW) // 8

typedef short short8 __attribute__((ext_vector_type(8)));
typedef float floatx4 __attribute__((ext_vector_type(4)));

__device__ __forceinline__ unsigned short f2bf(float f) {
  union { __hip_bfloat16 h; unsigned short u; } cv;
  cv.h = __float2bfloat16(f);
  return cv.u;
}

__device__ __forceinline__ float fast_tanh(float x) {
  float e = __expf(2.0f * x);
  return 1.0f - 2.0f / (e + 1.0f);
}

__device__ __forceinline__ void glds16(const void* g, void* l) {
  __builtin_amdgcn_global_load_lds(
      (const __attribute__((address_space(1))) void*)(uintptr_t)g,
      (__attribute__((address_space(3))) void*)(uint32_t)(uintptr_t)l,
      16, 0, 0);
}

// Fragment conventions (verified by R1-R6 passing kernels):
//  A-frag (16x16x32): lane holds A[m = l15][k = quad*8 + j], j=0..7 (16B)
//  B-frag:            lane holds B[n = l15][k = quad*8 + j]  (BT row-major)
//  C/D:               row = quad*4 + r, col = l15
// Packed buffers: frag f stored at [(f*64 + lane)*8] halves.
//  yPack: f = rb*16 + ks   (rb = batch-row/16: 0..511, ks = D k-step: 0..15)
//  w1p:   f = nb*16 + kb   (nb = H col-tile: 0..127,   kb = D k-step: 0..15)
//  w2p:   f = nb*64 + kb   (nb = D col-tile: 0..31,    kb = H k-step: 0..63)

__global__ __launch_bounds__(1024, 4) void fused_feval(
    const unsigned short* __restrict__ yPack,   // packed bf16 eval input
    const unsigned short* __restrict__ w1p,
    const unsigned short* __restrict__ w2p,
    const float* __restrict__ b1,
    const float* __restrict__ b2,
    const float* __restrict__ stateIn,   // EPI1: y fp32 ; EPI2: p fp32
    float* __restrict__ stateOut,        // EPI1: p      ; EPI2: ynew
    unsigned short* __restrict__ outPack,// packed bf16 next-eval input
    int epi) {                           // 1 or 2
  __shared__ unsigned short yA[32 * 512];       // 32 KB, frag (mt*16+ks)
  __shared__ unsigned short hA[2][32 * CW];     // 2 x 16 KB, frag (mt*8+ks)

  const int tid  = threadIdx.x;
  const int lane = tid & 63;
  const int w    = tid >> 6;    // wave 0..15
  const int quad = lane >> 4;
  const int l15  = lane & 15;
  const int blk  = blockIdx.x;  // 0..255
  const int B0   = blk * 32;    // slab base row

  // phase0: linear copy of this block's 32 KB packed y-slab into LDS.
  {
    const unsigned short* src = yPack + (size_t)blk * (32 * 512);
    glds16(src + (size_t)tid * 8, &yA[tid * 8]);
    glds16(src + (size_t)(1024 + tid) * 8, &yA[(1024 + tid) * 8]);
  }

  // preload the 8 per-chunk b1 biases (independent of the glds above)
  float bb1v[NCH];
#pragma unroll
  for (int c = 0; c < NCH; ++c) bb1v[c] = b1[c * CW + w * 16 + l15];

  __syncthreads();

  floatx4 accY[2][2] = {};  // [mt][i], cols w*32 + i*16 + l15

#pragma unroll
  for (int c = 0; c < NCH; ++c) {
    // ---- phase1: h[:, c*CW + w*16 .. +16] = tanh(y @ W1-slice + b1) ----
    // B-frag rotating prefetch: load b(ks+1) before the MFMAs of ks.
    floatx4 acc1[2] = {};
    const unsigned short* w1b =
        w1p + (size_t)(c * 16 + w) * 16 * 512 + (size_t)lane * 8;
    short8 bq = *(const short8*)w1b;
#pragma unroll
    for (int ks = 0; ks < 16; ++ks) {
      short8 bn;
      if (ks < 15) bn = *(const short8*)(w1b + (size_t)(ks + 1) * 512);
      short8 a0 = *(const short8*)&yA[((0 * 16 + ks) * 64 + lane) * 8];
      short8 a1 = *(const short8*)&yA[((1 * 16 + ks) * 64 + lane) * 8];
      acc1[0] = __builtin_amdgcn_mfma_f32_16x16x32_bf16(a0, bq, acc1[0], 0, 0, 0);
      acc1[1] = __builtin_amdgcn_mfma_f32_16x16x32_bf16(a1, bq, acc1[1], 0, 0, 0);
      if (ks < 15) bq = bn;
    }

    // early-issue phase2(c-1)'s first B-pair: its L2 latency hides under
    // the tanh/cvt scatter below (~500 VALU cycles).
    short8 pb0, pb1;
    const unsigned short* w2b0 = nullptr;
    const unsigned short* w2b1 = nullptr;
    if (c > 0) {
      const int kb0 = (c - 1) * 8;
      w2b0 = w2p + ((size_t)((w * 2 + 0) * 64 + kb0) * 64 + lane) * 8;
      w2b1 = w2p + ((size_t)((w * 2 + 1) * 64 + kb0) * 64 + lane) * 8;
      pb0 = *(const short8*)w2b0;
      pb1 = *(const short8*)w2b1;
    }

    // bias + tanh + scatter into hA[c&1] in A-frag layout (k = h-col in chunk)
    {
      unsigned short* hbuf = hA[c & 1];
      const int kloc = w * 16 + l15;        // 0..255 (this lane's h-col)
      const float bb = bb1v[c];
      const int ksa = kloc >> 5;
      const int qa  = (kloc & 31) >> 3;
      const int kb7 = kloc & 7;
#pragma unroll
      for (int mt = 0; mt < 2; ++mt)
#pragma unroll
        for (int r = 0; r < 4; ++r) {
          const int m15 = quad * 4 + r;     // C row -> A-frag m
          hbuf[((mt * 8 + ksa) * 64 + qa * 16 + m15) * 8 + kb7] =
              f2bf(fast_tanh(acc1[mt][r] + bb));
        }
    }

    // ---- phase2 for chunk c-1: accY += h_prev @ W2-slice (B rotated) ----
    if (c > 0) {
      const unsigned short* hp = hA[(c - 1) & 1];
#pragma unroll
      for (int ks = 0; ks < 8; ++ks) {
        short8 nb0, nb1_;
        if (ks < 7) {
          nb0  = *(const short8*)(w2b0 + (size_t)(ks + 1) * 512);
          nb1_ = *(const short8*)(w2b1 + (size_t)(ks + 1) * 512);
        }
        short8 ha0 = *(const short8*)&hp[((0 * 8 + ks) * 64 + lane) * 8];
        short8 ha1 = *(const short8*)&hp[((1 * 8 + ks) * 64 + lane) * 8];
        accY[0][0] = __builtin_amdgcn_mfma_f32_16x16x32_bf16(ha0, pb0, accY[0][0], 0, 0, 0);
        accY[1][0] = __builtin_amdgcn_mfma_f32_16x16x32_bf16(ha1, pb0, accY[1][0], 0, 0, 0);
        accY[0][1] = __builtin_amdgcn_mfma_f32_16x16x32_bf16(ha0, pb1, accY[0][1], 0, 0, 0);
        accY[1][1] = __builtin_amdgcn_mfma_f32_16x16x32_bf16(ha1, pb1, accY[1][1], 0, 0, 0);
        if (ks < 7) { pb0 = nb0; pb1 = nb1_; }
      }
    }
    __syncthreads();
  }
  // tail phase2: chunk NCH-1 (buffer (NCH-1)&1 = 1), same rotation
  {
    const unsigned short* hp = hA[(NCH - 1) & 1];
    const int kb0 = (NCH - 1) * 8;
    const unsigned short* w2b0 =
        w2p + ((size_t)((w * 2 + 0) * 64 + kb0) * 64 + lane) * 8;
    const unsigned short* w2b1 =
        w2p + ((size_t)((w * 2 + 1) * 64 + kb0) * 64 + lane) * 8;
    short8 pb0 = *(const short8*)w2b0;
    short8 pb1 = *(const short8*)w2b1;
#pragma unroll
    for (int ks = 0; ks < 8; ++ks) {
      short8 nb0, nb1_;
      if (ks < 7) {
        nb0  = *(const short8*)(w2b0 + (size_t)(ks + 1) * 512);
        nb1_ = *(const short8*)(w2b1 + (size_t)(ks + 1) * 512);
      }
      short8 ha0 = *(const short8*)&hp[((0 * 8 + ks) * 64 + lane) * 8];
      short8 ha1 = *(const short8*)&hp[((1 * 8 + ks) * 64 + lane) * 8];
      accY[0][0] = __builtin_amdgcn_mfma_f32_16x16x32_bf16(ha0, pb0, accY[0][0], 0, 0, 0);
      accY[1][0] = __builtin_amdgcn_mfma_f32_16x16x32_bf16(ha1, pb0, accY[1][0], 0, 0, 0);
      accY[0][1] = __builtin_amdgcn_mfma_f32_16x16x32_bf16(ha0, pb1, accY[0][1], 0, 0, 0);
      accY[1][1] = __builtin_amdgcn_mfma_f32_16x16x32_bf16(ha1, pb1, accY[1][1], 0, 0, 0);
      if (ks < 7) { pb0 = nb0; pb1 = nb1_; }
    }
  }
  __syncthreads();  // all waves done reading hA before reuse as pack staging

  // Epilogue: add b2, Heun combine with fp32 state, pack bf16 result.
  {
    unsigned short* pbuf = &hA[0][0];  // 32 KB staging, yPack layout (mt*16+ksa)
#pragma unroll
    for (int i = 0; i < 2; ++i) {
      const int ncol = w * 32 + i * 16 + l15;  // 0..511
      const float bb = b2[ncol];
      const int ksa = ncol >> 5;
      const int qa  = (ncol & 31) >> 3;
      const int nb7 = ncol & 7;
#pragma unroll
      for (int mt = 0; mt < 2; ++mt)
#pragma unroll
        for (int r = 0; r < 4; ++r) {
          const int row = B0 + mt * 16 + quad * 4 + r;
          const size_t idx = (size_t)row * DDIM + ncol;
          const float v = accY[mt][i][r] + bb;
          float nv;
          if (epi == 1) {
            const float y = stateIn[idx];
            stateOut[idx] = y + 0.05f * v;   // p = y + (dt/2)*k1
            nv = y + 0.1f * v;               // ymid
          } else {
            const float yn = stateIn[idx] + 0.05f * v;  // ynew = p + (dt/2)*k2
            stateOut[idx] = yn;
            nv = yn;
          }
          const int m15 = quad * 4 + r;
          pbuf[((mt * 16 + ksa) * 64 + qa * 16 + m15) * 8 + nb7] = f2bf(nv);
        }
    }
    __syncthreads();
    unsigned short* dst = outPack + (size_t)blk * (32 * 512);
#pragma unroll
    for (int p = 0; p < 2; ++p) {
      short8 v = *(const short8*)&pbuf[(size_t)(p * 1024 + tid) * 8];
      *(short8*)&dst[(size_t)(p * 1024 + tid) * 8] = v;
    }
  }
}

// Pack weight [K][N] fp32 -> B-frag order: frag f = nb*KB + kb,
// lane entry = src[kb*32 + quad*8 + j][nb*16 + l15].
__global__ void pack_b(const float* __restrict__ src, unsigned short* __restrict__ dst,
                       int KB, int N) {
  const int t = blockIdx.x * 256 + threadIdx.x;
  const int lane = t & 63, f = t >> 6;
  const int nb = f / KB, kb = f % KB;
  const int quad = lane >> 4, l15 = lane & 15;
  const int k0 = kb * 32 + quad * 8, n = nb * 16 + l15;
  short8 v;
#pragma unroll
  for (int j = 0; j < 8; ++j)
    v[j] = (short)f2bf(src[(size_t)(k0 + j) * N + n]);
  *(short8*)&dst[(size_t)t * 8] = v;
}

// y0 fp32 [8192][512] -> yF fp32 copy + packed bf16 A-frags.
__global__ void pack_y(const float* __restrict__ y0, float* __restrict__ yF,
                       unsigned short* __restrict__ ypk) {
  const int t = blockIdx.x * 256 + threadIdx.x;
  const int lane = t & 63, f = t >> 6;
  const int rb = f >> 4, ks = f & 15;
  const int quad = lane >> 4, l15 = lane & 15;
  const int row = rb * 16 + l15, c0 = ks * 32 + quad * 8;
  short8 v;
#pragma unroll
  for (int j = 0; j < 8; ++j) {
    const float x = y0[(size_t)row * DDIM + c0 + j];
    yF[(size_t)row * DDIM + c0 + j] = x;
    v[j] = (short)f2bf(x);
  }
  *(short8*)&ypk[(size_t)t * 8] = v;
}

extern "C" void kernel_launch(void* const* d_in, const int* in_sizes, int n_in,
                              void* d_out, int out_size, void* d_ws, size_t ws_size,
                              hipStream_t stream) {
  const float* y0 = (const float*)d_in[0];
  const float* W1 = (const float*)d_in[1];  // [512][2048]
  const float* b1 = (const float*)d_in[2];  // [2048]
  const float* W2 = (const float*)d_in[3];  // [2048][512]
  const float* b2 = (const float*)d_in[4];  // [512]

  char* ws = (char*)d_ws;
  float*          yF   = (float*)(ws);                         // 16 MB
  float*          pF   = (float*)(ws + (size_t)(16u << 20));   // 16 MB
  unsigned short* ypk  = (unsigned short*)(ws + (size_t)(32u << 20)); // 8 MB
  unsigned short* ympk = (unsigned short*)(ws + (size_t)(40u << 20)); // 8 MB
  unsigned short* w1p  = (unsigned short*)(ws + (size_t)(48u << 20)); // 2 MB
  unsigned short* w2p  = (unsigned short*)(ws + (size_t)(50u << 20)); // 2 MB

  // Pre-pass: pack weights (2048 frags each) and y0 (8192 frags).
  pack_b<<<512, 256, 0, stream>>>(W1, w1p, 16, HDIM);
  pack_b<<<512, 256, 0, stream>>>(W2, w2p, 64, DDIM);
  pack_y<<<2048, 256, 0, stream>>>(y0, yF, ypk);

  const dim3 grid(256), blkd(1024);
  for (int s = 0; s < 10; ++s) {
    // eval1: k1 = f(y); p = y + 0.05*k1; ymid = y + 0.1*k1 (packed)
    fused_feval<<<grid, blkd, 0, stream>>>(ypk, w1p, w2p, b1, b2, yF, pF, ympk, 1);
    // eval2: k2 = f(ymid); ynew = p + 0.05*k2 (fp32 + packed)
    float* yOut = (s == 9) ? (float*)d_out : yF;
    fused_feval<<<grid, blkd, 0, stream>>>(ympk, w1p, w2p, b1, b2, pF, yOut, ypk, 2);
  }
}